// Round 10
// baseline (283.898 us; speedup 1.0000x reference)
//
#include <hip/hip_runtime.h>
#include <math.h>

#define KK 64
#define DD 256
#define GX 256        // blocks per feature; grid = 512 = 2 blocks/CU
#define CH 32         // rows per chunk (2 x K=16 MFMA steps)
#define MAXCHUNK 512  // max rows per block (N <= GX*MAXCHUNK)
#define INV_TAU 2.0f
#define EPSL 1e-8f

typedef unsigned int u32;
typedef __attribute__((ext_vector_type(4))) u32 u32x4;
typedef __attribute__((ext_vector_type(8))) short s16x8;
typedef __attribute__((ext_vector_type(16))) float f32x16;

__device__ __forceinline__ u32 f2bf(float f) {
    u32 u = __builtin_bit_cast(u32, f);
    return (u + 0x7FFFu + ((u >> 16) & 1u)) >> 16;
}

// ws float layout:
// P : [2][GX][K*D]; C : [2][GX][K]; AR : [2][K*D]; lossk : [K]; scratch : [8]

__global__ __launch_bounds__(512, 4) void seg_mfma_kernel(
    const float* __restrict__ fa, const float* __restrict__ fr,
    const int* __restrict__ la, const int* __restrict__ lr,
    float* __restrict__ P, float* __restrict__ C, int N)
{
    __shared__ __attribute__((aligned(16))) float tile[8][CH * 32]; // 4 KB per wave
    __shared__ int lbl[MAXCHUNK];
    __shared__ int cnt[KK];

    const int tid = threadIdx.x;
    const int g = blockIdx.x, f = blockIdx.y;
    const float* __restrict__ feat = f ? fr : fa;
    const int* __restrict__ label = f ? lr : la;

    if (tid < KK) cnt[tid] = 0;

    const int chunkR = (N + GX - 1) / GX;
    const int n0 = g * chunkR;
    int rows = min(N, n0 + chunkR) - n0;
    if (rows < 0) rows = 0;

    __syncthreads();
    for (int i = tid; i < rows; i += 512) lbl[i] = label[n0 + i];
    __syncthreads();
    for (int i = tid; i < rows; i += 512) atomicAdd(&cnt[lbl[i]], 1);

    const int w = tid >> 6, lane = tid & 63;
    const int half = lane >> 5;       // MFMA K half-group
    const int nn = lane & 31;         // class-in-group / col-in-strip
    const int col0 = w * 32;          // wave owns 32 columns
    const int a = lane >> 3;          // load sub-row 0..7
    const int q4 = lane & 7;          // load col-quad 0..7
    float* tw = &tile[w][0];

    f32x16 acc0 = {0.0f}, acc1 = {0.0f};
    const int nfull = rows / CH;

    // stream4-identical loads: 1 float4/lane/inst = 8 full 128B lines per inst
    #define LOADF(dst, t)                                                        \
    do {                                                                         \
        _Pragma("unroll")                                                        \
        for (int s_ = 0; s_ < 4; ++s_)                                           \
            dst[s_] = *(const float4*)(feat +                                    \
                (size_t)(n0 + (t) * CH + s_ * 8 + a) * DD + col0 + q4 * 4);      \
    } while (0)

    #define PACK_MFMA(fv, lv)                                                    \
    do {                                                                         \
        u32 a0p[4], a1p[4], bpk[4];                                              \
        _Pragma("unroll")                                                        \
        for (int p_ = 0; p_ < 4; ++p_) {                                         \
            const int j0_ = 2 * p_, j1_ = 2 * p_ + 1;                            \
            a0p[p_] = ((lv[j0_] == nn)      ? 0x3F80u : 0u) |                    \
                      ((lv[j1_] == nn)      ? 0x3F800000u : 0u);                 \
            a1p[p_] = ((lv[j0_] == nn + 32) ? 0x3F80u : 0u) |                    \
                      ((lv[j1_] == nn + 32) ? 0x3F800000u : 0u);                 \
            bpk[p_] = f2bf(fv[j0_]) | (f2bf(fv[j1_]) << 16);                     \
        }                                                                        \
        const s16x8 A0 = __builtin_bit_cast(s16x8, (u32x4){a0p[0], a0p[1], a0p[2], a0p[3]}); \
        const s16x8 A1 = __builtin_bit_cast(s16x8, (u32x4){a1p[0], a1p[1], a1p[2], a1p[3]}); \
        const s16x8 Bf = __builtin_bit_cast(s16x8, (u32x4){bpk[0], bpk[1], bpk[2], bpk[3]}); \
        acc0 = __builtin_amdgcn_mfma_f32_32x32x16_bf16(A0, Bf, acc0, 0, 0, 0);   \
        acc1 = __builtin_amdgcn_mfma_f32_32x32x16_bf16(A1, Bf, acc1, 0, 0, 0);   \
    } while (0)

    // consume one 32-row chunk: regs -> wave-private LDS -> fragments -> 4 MFMA
    #define PROC(buf, t)                                                         \
    do {                                                                         \
        _Pragma("unroll")                                                        \
        for (int s_ = 0; s_ < 4; ++s_)                                           \
            *(float4*)(tw + (s_ * 8 + a) * 32 + q4 * 4) = buf[s_];               \
        _Pragma("unroll")                                                        \
        for (int kk_ = 0; kk_ < 2; ++kk_) {                                      \
            float fv[8]; int lv[8];                                              \
            const int rb_ = (t) * CH + kk_ * 16 + half * 8;                      \
            _Pragma("unroll")                                                    \
            for (int j_ = 0; j_ < 8; ++j_) {                                     \
                fv[j_] = tw[(kk_ * 16 + half * 8 + j_) * 32 + nn];               \
                lv[j_] = lbl[rb_ + j_];                                          \
            }                                                                    \
            PACK_MFMA(fv, lv);                                                   \
        }                                                                        \
    } while (0)

    float4 bufA[4], bufB[4];
    if (nfull > 0) LOADF(bufA, 0);
    if (nfull > 1) LOADF(bufB, 1);
    int t = 0;
    for (; t + 2 <= nfull; t += 2) {
        PROC(bufA, t);
        if (t + 2 < nfull) LOADF(bufA, t + 2);
        PROC(bufB, t + 1);
        if (t + 3 < nfull) LOADF(bufB, t + 3);
    }
    if (t < nfull) PROC(bufA, t);

    // tail (rows % 32), clamped direct loads
    const int r0t = nfull * CH;
    if (r0t < rows) {
        #pragma unroll
        for (int kk = 0; kk < 2; ++kk) {
            const int rb = r0t + kk * 16 + half * 8;
            float tv[8]; int lv[8];
            #pragma unroll
            for (int j = 0; j < 8; ++j) {
                const int rr = rb + j;
                lv[j] = (rr < rows) ? lbl[rr] : -1;
                tv[j] = feat[(size_t)(n0 + ((rr < rows) ? rr : 0)) * DD + col0 + nn];
            }
            PACK_MFMA(tv, lv);
        }
    }
    #undef LOADF
    #undef PACK_MFMA
    #undef PROC

    float* dstb = P + ((size_t)f * GX + g) * (KK * DD);
    #pragma unroll
    for (int rg = 0; rg < 16; ++rg) {
        const int cls = (rg & 3) + 8 * (rg >> 2) + 4 * half;
        dstb[(size_t)cls * DD + col0 + nn] = acc0[rg];
        dstb[(size_t)(cls + 32) * DD + col0 + nn] = acc1[rg];
    }
    __syncthreads();
    if (tid < KK) C[((size_t)f * GX + g) * KK + tid] = (float)cnt[tid];
}

// ---------- diagnostic probes (write only to ws scratch) ----------

__device__ __forceinline__ void probe_flush(float s, float* slot) {
    #pragma unroll
    for (int d = 1; d < 64; d <<= 1) s += __shfl_xor(s, d, 64);
    __shared__ float red[8];
    const int tid = threadIdx.x;
    if ((tid & 63) == 0) red[tid >> 6] = s;
    __syncthreads();
    if (tid == 0) {
        float t = 0;
        #pragma unroll
        for (int u = 0; u < 8; ++u) t += red[u];
        atomicAdd(slot, t);
    }
}

__global__ __launch_bounds__(512, 4) void probe_stream4(
    const float* __restrict__ fa, const float* __restrict__ fr,
    float* __restrict__ scratch, int N)
{
    const int tid = threadIdx.x, g = blockIdx.x, f = blockIdx.y;
    const float* feat = f ? fr : fa;
    const int chunkR = (N + GX - 1) / GX;
    const int n0 = g * chunkR;
    int rows = min(N, n0 + chunkR) - n0;
    if (rows < 0) rows = 0;
    const float4* p = (const float4*)(feat + (size_t)n0 * DD);
    const int nf4 = rows * (DD / 4);
    float s = 0.0f;
    int i = tid;
    for (; i + 512 * 7 < nf4; i += 512 * 8) {
        float4 v[8];
        #pragma unroll
        for (int u = 0; u < 8; ++u) v[u] = p[i + 512 * u];
        #pragma unroll
        for (int u = 0; u < 8; ++u) s += v[u].x + v[u].y + v[u].z + v[u].w;
    }
    for (; i < nf4; i += 512) { float4 v = p[i]; s += v.x + v.y + v.z + v.w; }
    probe_flush(s, &scratch[f]);
}

__global__ __launch_bounds__(512, 4) void probe_stream1(
    const float* __restrict__ fa, const float* __restrict__ fr,
    float* __restrict__ scratch, int N)
{
    const int tid = threadIdx.x, g = blockIdx.x, f = blockIdx.y;
    const float* feat = f ? fr : fa;
    const int chunkR = (N + GX - 1) / GX;
    const int n0 = g * chunkR;
    int rows = min(N, n0 + chunkR) - n0;
    if (rows < 0) rows = 0;
    const int w = tid >> 6, lane = tid & 63;
    const int col = w * 32 + (lane & 31);
    const int half = lane >> 5;
    const int nfull = rows / 16;
    float s = 0.0f;
    for (int t = 0; t < nfull; ++t) {
        const float* bp = feat + (size_t)(n0 + t * 16 + half * 8) * DD + col;
        float v[8];
        #pragma unroll
        for (int j = 0; j < 8; ++j) v[j] = bp[j * DD];
        #pragma unroll
        for (int j = 0; j < 8; ++j) s += v[j];
    }
    probe_flush(s, &scratch[2 + f]);
}

__global__ __launch_bounds__(512, 4) void probe_ilv4(
    const float* __restrict__ fa, const float* __restrict__ fr,
    float* __restrict__ scratch, int N)
{
    const int tid = threadIdx.x, f = blockIdx.y;
    const float* feat = f ? fr : fa;
    const float4* p = (const float4*)feat;
    const size_t nf4 = (size_t)N * (DD / 4);
    const size_t stride = (size_t)GX * 512;
    size_t i = (size_t)blockIdx.x * 512 + tid;
    float s = 0.0f;
    for (; i + stride * 7 < nf4; i += stride * 8) {
        float4 v[8];
        #pragma unroll
        for (int u = 0; u < 8; ++u) v[u] = p[i + stride * u];
        #pragma unroll
        for (int u = 0; u < 8; ++u) s += v[u].x + v[u].y + v[u].z + v[u].w;
    }
    for (; i < nf4; i += stride) { float4 v = p[i]; s += v.x + v.y + v.z + v.w; }
    probe_flush(s, &scratch[4 + f]);
}

// ---------- downstream (unchanged, proven) ----------

__global__ __launch_bounds__(256) void proto_norm_kernel(
    const float* __restrict__ P, const float* __restrict__ C,
    float* __restrict__ AR, int G)
{
    const int k = blockIdx.x, f = blockIdx.y, tid = threadIdx.x;
    const float* base = P + (size_t)f * G * (KK * DD) + (size_t)k * DD + tid;

    float s = 0.0f;
    int g = 0;
    for (; g + 8 <= G; g += 8) {
        float v[8];
        #pragma unroll
        for (int u = 0; u < 8; ++u) v[u] = base[(size_t)(g + u) * (KK * DD)];
        #pragma unroll
        for (int u = 0; u < 8; ++u) s += v[u];
    }
    for (; g < G; ++g) s += base[(size_t)g * (KK * DD)];

    float c = 0.0f;
    const float* cb = C + (size_t)f * G * KK + k;
    for (int g2 = 0; g2 < G; ++g2) c += cb[(size_t)g2 * KK];

    const float m = s / c;
    float sq = m * m;
    #pragma unroll
    for (int i = 1; i < 64; i <<= 1) sq += __shfl_xor(sq, i, 64);
    __shared__ float red[4];
    const int wid = tid >> 6, lane = tid & 63;
    if (lane == 0) red[wid] = sq;
    __syncthreads();
    const float nrm = red[0] + red[1] + red[2] + red[3];
    AR[(size_t)f * KK * DD + (size_t)k * DD + tid] = m / fmaxf(sqrtf(nrm), 1e-12f);
}

__global__ __launch_bounds__(256) void loss_kernel(const float* __restrict__ AR,
                                                   float* __restrict__ lossk)
{
    const float* A = AR;
    const float* R = AR + KK * DD;
    const int k = blockIdx.x, tid = threadIdx.x;

    const float a = A[k * DD + tid];
    const float r = R[k * DD + tid];
    const float lfp = a * r * INV_TAU;
    const float fp = expf(lfp);
    float ssa = 0.0f, ssr = 0.0f;
    #pragma unroll 8
    for (int j = 0; j < KK; ++j) {
        ssa += expf(a * A[j * DD + tid] * INV_TAU);
        ssr += expf(a * R[j * DD + tid] * INV_TAU);
    }
    const float Fn = (ssa - expf(a * a * INV_TAU)) + (ssr - fp) + 2.0f * (KK - 1) * fp;
    float l = logf(Fn + EPSL) - lfp;

    #pragma unroll
    for (int i = 1; i < 64; i <<= 1) l += __shfl_xor(l, i, 64);
    __shared__ float red[4];
    const int wid = tid >> 6, lane = tid & 63;
    if (lane == 0) red[wid] = l;
    __syncthreads();
    if (tid == 0) lossk[k] = (red[0] + red[1] + red[2] + red[3]) * (1.0f / DD);
}

__global__ void final_kernel(const float* __restrict__ lossk, float* __restrict__ out)
{
    float v = lossk[threadIdx.x];
    #pragma unroll
    for (int i = 1; i < 64; i <<= 1) v += __shfl_xor(v, i, 64);
    if (threadIdx.x == 0) out[0] = v;
}

extern "C" void kernel_launch(void* const* d_in, const int* in_sizes, int n_in,
                              void* d_out, int out_size, void* d_ws, size_t ws_size,
                              hipStream_t stream)
{
    const float* fa = (const float*)d_in[0];
    const float* fr = (const float*)d_in[1];
    const int* la = (const int*)d_in[2];
    const int* lr = (const int*)d_in[3];
    float* ws = (float*)d_ws;
    float* out = (float*)d_out;
    const int N = in_sizes[2];

    float* P = ws;                                  // [2][GX][K*D]
    float* C = P + 2L * GX * KK * DD;               // [2][GX][K]
    float* AR = C + 2L * GX * KK;                   // [2][K*D]
    float* lossk = AR + 2L * KK * DD;               // [K]
    float* scratch = lossk + KK;                    // [8] probe slots

    hipMemsetAsync(scratch, 0, 8 * sizeof(float), stream);

    seg_mfma_kernel<<<dim3(GX, 2), 512, 0, stream>>>(fa, fr, la, lr, P, C, N);
    proto_norm_kernel<<<dim3(KK, 2), 256, 0, stream>>>(P, C, AR, GX);
    loss_kernel<<<KK, 256, 0, stream>>>(AR, lossk);
    final_kernel<<<1, 64, 0, stream>>>(lossk, out);

    // diagnostic probes (after output is produced; write only to scratch)
    probe_stream4<<<dim3(GX, 2), 512, 0, stream>>>(fa, fr, scratch, N);
    probe_stream1<<<dim3(GX, 2), 512, 0, stream>>>(fa, fr, scratch, N);
    probe_ilv4<<<dim3(GX, 2), 512, 0, stream>>>(fa, fr, scratch, N);
}

// Round 11
// 274.200 us; speedup vs baseline: 1.0354x; 1.0354x over previous
//
#include <hip/hip_runtime.h>
#include <math.h>

#define KK 64
#define DD 256
#define GX 256        // blocks per feature; grid = 512 = 2 blocks/CU
#define CH 32         // rows per chunk (32 KB tile, 2 x K=16 MFMA steps)
#define MAXCHUNK 512  // max rows per block (N <= GX*MAXCHUNK)
#define INV_TAU 2.0f
#define EPSL 1e-8f

typedef unsigned int u32;
typedef __attribute__((ext_vector_type(4))) u32 u32x4;
typedef __attribute__((ext_vector_type(8))) short s16x8;
typedef __attribute__((ext_vector_type(16))) float f32x16;

__device__ __forceinline__ u32 f2bf(float f) {
    u32 u = __builtin_bit_cast(u32, f);
    return (u + 0x7FFFu + ((u >> 16) & 1u)) >> 16;
}

// ws float layout:
// P : [2][GX][K*D]; C : [2][GX][K]; AR : [2][K*D]; lossk : [K]; scratch : [8]

__global__ __launch_bounds__(512, 4) void seg_mfma_kernel(
    const float* __restrict__ fa, const float* __restrict__ fr,
    const int* __restrict__ la, const int* __restrict__ lr,
    float* __restrict__ P, float* __restrict__ C, int N)
{
    __shared__ __attribute__((aligned(16))) float tile[2][CH * DD]; // 2 x 32 KB
    __shared__ int lbl[MAXCHUNK];
    __shared__ int cnt[KK];

    const int tid = threadIdx.x;
    const int g = blockIdx.x, f = blockIdx.y;
    const float* __restrict__ feat = f ? fr : fa;
    const int* __restrict__ label = f ? lr : la;

    if (tid < KK) cnt[tid] = 0;

    const int chunkR = (N + GX - 1) / GX;
    const int n0 = g * chunkR;
    int rows = min(N, n0 + chunkR) - n0;
    if (rows < 0) rows = 0;

    __syncthreads();
    for (int i = tid; i < rows; i += 512) lbl[i] = label[n0 + i];
    __syncthreads();
    for (int i = tid; i < rows; i += 512) atomicAdd(&cnt[lbl[i]], 1);

    const int w = tid >> 6, lane = tid & 63;
    const int half = lane >> 5;       // MFMA K half-group
    const int nn = lane & 31;         // class-in-group / col-in-strip
    const int col0 = w * 32;          // wave owns cols [32w, 32w+32)

    f32x16 acc0 = {0.0f}, acc1 = {0.0f};
    const int nfull = rows / CH;

    // stream4-identical loads: wave w reads a CONTIGUOUS 4 KB slice of the
    // 32 KB chunk (rows t*32+4w .. +4w+3), 4 x float4 (1 KB contiguous/inst)
    #define LOADR(buf, t)                                                        \
    do {                                                                         \
        const float* src_ = feat + (size_t)(n0 + (t) * CH) * DD + w * 1024 + lane * 4; \
        _Pragma("unroll")                                                        \
        for (int i_ = 0; i_ < 4; ++i_)                                           \
            buf[i_] = *(const float4*)(src_ + i_ * 256);                         \
    } while (0)

    // write the slice to the block tile, row-major [32][256], contiguous b128
    #define WRITES(dstT, buf)                                                    \
    do {                                                                         \
        float* d_ = (dstT) + w * 1024 + lane * 4;                                \
        _Pragma("unroll")                                                        \
        for (int i_ = 0; i_ < 4; ++i_)                                           \
            *(float4*)(d_ + i_ * 256) = buf[i_];                                 \
    } while (0)

    #define PACK_MFMA(fv, lv)                                                    \
    do {                                                                         \
        u32 a0p[4], a1p[4], bpk[4];                                              \
        _Pragma("unroll")                                                        \
        for (int p_ = 0; p_ < 4; ++p_) {                                         \
            const int j0_ = 2 * p_, j1_ = 2 * p_ + 1;                            \
            a0p[p_] = ((lv[j0_] == nn)      ? 0x3F80u : 0u) |                    \
                      ((lv[j1_] == nn)      ? 0x3F800000u : 0u);                 \
            a1p[p_] = ((lv[j0_] == nn + 32) ? 0x3F80u : 0u) |                    \
                      ((lv[j1_] == nn + 32) ? 0x3F800000u : 0u);                 \
            bpk[p_] = f2bf(fv[j0_]) | (f2bf(fv[j1_]) << 16);                     \
        }                                                                        \
        const s16x8 A0 = __builtin_bit_cast(s16x8, (u32x4){a0p[0], a0p[1], a0p[2], a0p[3]}); \
        const s16x8 A1 = __builtin_bit_cast(s16x8, (u32x4){a1p[0], a1p[1], a1p[2], a1p[3]}); \
        const s16x8 Bf = __builtin_bit_cast(s16x8, (u32x4){bpk[0], bpk[1], bpk[2], bpk[3]}); \
        acc0 = __builtin_amdgcn_mfma_f32_32x32x16_bf16(A0, Bf, acc0, 0, 0, 0);   \
        acc1 = __builtin_amdgcn_mfma_f32_32x32x16_bf16(A1, Bf, acc1, 0, 0, 0);   \
    } while (0)

    // consume the block tile: wave reads its column strip (2 lanes/bank = free)
    #define CONSUME(tp, t)                                                       \
    do {                                                                         \
        _Pragma("unroll")                                                        \
        for (int kk_ = 0; kk_ < 2; ++kk_) {                                      \
            float fv[8]; int lv[8];                                              \
            const int rb_ = (t) * CH + kk_ * 16 + half * 8;                      \
            _Pragma("unroll")                                                    \
            for (int j_ = 0; j_ < 8; ++j_) {                                     \
                fv[j_] = (tp)[(kk_ * 16 + half * 8 + j_) * DD + col0 + nn];      \
                lv[j_] = lbl[rb_ + j_];                                          \
            }                                                                    \
            PACK_MFMA(fv, lv);                                                   \
        }                                                                        \
    } while (0)

    // pipeline: raw s_barrier + lgkmcnt(0) ONLY (no vmcnt drain at barriers!)
    // so the next chunk's global loads stay in flight across the barrier (T4).
    float4 buf[4];
    int cur = 0;
    if (nfull > 0) {
        LOADR(buf, 0);
        asm volatile("s_waitcnt vmcnt(0)" ::: "memory");
        WRITES(tile[0], buf);
        if (nfull > 1) LOADR(buf, 1);
        asm volatile("s_waitcnt lgkmcnt(0)" ::: "memory");
        __builtin_amdgcn_s_barrier();
    }
    for (int t = 0; t < nfull; ++t) {
        const float* tp = tile[cur];
        CONSUME(tp, t);
        if (t + 1 < nfull) {
            asm volatile("s_waitcnt vmcnt(0)" ::: "memory");   // chunk t+1 landed
            WRITES(tile[cur ^ 1], buf);
            if (t + 2 < nfull) LOADR(buf, t + 2);              // issue ahead
            asm volatile("s_waitcnt lgkmcnt(0)" ::: "memory"); // my ds_writes done
            __builtin_amdgcn_s_barrier();                      // visible to all
            cur ^= 1;
        }
    }

    // tail (rows % 32), clamped direct loads (off hot path)
    const int r0t = nfull * CH;
    if (r0t < rows) {
        #pragma unroll
        for (int kk = 0; kk < 2; ++kk) {
            const int rb = r0t + kk * 16 + half * 8;
            float tv[8]; int lv[8];
            #pragma unroll
            for (int j = 0; j < 8; ++j) {
                const int rr = rb + j;
                lv[j] = (rr < rows) ? lbl[rr] : -1;
                tv[j] = feat[(size_t)(n0 + ((rr < rows) ? rr : 0)) * DD + col0 + nn];
            }
            PACK_MFMA(tv, lv);
        }
    }
    #undef LOADR
    #undef WRITES
    #undef PACK_MFMA
    #undef CONSUME

    float* dstb = P + ((size_t)f * GX + g) * (KK * DD);
    #pragma unroll
    for (int rg = 0; rg < 16; ++rg) {
        const int cls = (rg & 3) + 8 * (rg >> 2) + 4 * half;
        dstb[(size_t)cls * DD + col0 + nn] = acc0[rg];
        dstb[(size_t)(cls + 32) * DD + col0 + nn] = acc1[rg];
    }
    __syncthreads();
    if (tid < KK) C[((size_t)f * GX + g) * KK + tid] = (float)cnt[tid];
}

// ---------- diagnostic probes (2-rep so they enter top-5; ws scratch only) ----------

__device__ __forceinline__ void probe_flush(float s, float* slot) {
    #pragma unroll
    for (int d = 1; d < 64; d <<= 1) s += __shfl_xor(s, d, 64);
    __shared__ float red[8];
    const int tid = threadIdx.x;
    if ((tid & 63) == 0) red[tid >> 6] = s;
    __syncthreads();
    if (tid == 0) {
        float t = 0;
        #pragma unroll
        for (int u = 0; u < 8; ++u) t += red[u];
        atomicAdd(slot, t);
    }
}

// strided pattern (R8's): dword loads, 128 B used per 1 KB row
__global__ __launch_bounds__(512, 4) void probe_stream1_x2(
    const float* __restrict__ fa, const float* __restrict__ fr,
    float* __restrict__ scratch, int N)
{
    const int tid = threadIdx.x, g = blockIdx.x, f = blockIdx.y;
    const float* feat = f ? fr : fa;
    const int chunkR = (N + GX - 1) / GX;
    const int n0 = g * chunkR;
    int rows = min(N, n0 + chunkR) - n0;
    if (rows < 0) rows = 0;
    const int w = tid >> 6, lane = tid & 63;
    const int col = w * 32 + (lane & 31);
    const int half = lane >> 5;
    const int nfull = rows / 16;
    float s = 0.0f;
    for (int rep = 0; rep < 2; ++rep) {
        for (int t = 0; t < nfull; ++t) {
            const float* bp = feat + (size_t)(n0 + t * 16 + half * 8) * DD + col;
            float v[8];
            #pragma unroll
            for (int j = 0; j < 8; ++j) v[j] = bp[j * DD];
            #pragma unroll
            for (int j = 0; j < 8; ++j) s += v[j];
        }
        asm volatile("" ::: "memory");   // force真 re-load on rep 2
    }
    probe_flush(s, &scratch[f]);
}

// contiguous float4 pattern over the same chunk layout
__global__ __launch_bounds__(512, 4) void probe_stream4_x2(
    const float* __restrict__ fa, const float* __restrict__ fr,
    float* __restrict__ scratch, int N)
{
    const int tid = threadIdx.x, g = blockIdx.x, f = blockIdx.y;
    const float* feat = f ? fr : fa;
    const int chunkR = (N + GX - 1) / GX;
    const int n0 = g * chunkR;
    int rows = min(N, n0 + chunkR) - n0;
    if (rows < 0) rows = 0;
    const float4* p = (const float4*)(feat + (size_t)n0 * DD);
    const int nf4 = rows * (DD / 4);
    float s = 0.0f;
    for (int rep = 0; rep < 2; ++rep) {
        int i = tid;
        for (; i + 512 * 7 < nf4; i += 512 * 8) {
            float4 v[8];
            #pragma unroll
            for (int u = 0; u < 8; ++u) v[u] = p[i + 512 * u];
            #pragma unroll
            for (int u = 0; u < 8; ++u) s += v[u].x + v[u].y + v[u].z + v[u].w;
        }
        for (; i < nf4; i += 512) { float4 v = p[i]; s += v.x + v.y + v.z + v.w; }
        asm volatile("" ::: "memory");
    }
    probe_flush(s, &scratch[2 + f]);
}

// ---------- downstream (unchanged, proven) ----------

__global__ __launch_bounds__(256) void proto_norm_kernel(
    const float* __restrict__ P, const float* __restrict__ C,
    float* __restrict__ AR, int G)
{
    const int k = blockIdx.x, f = blockIdx.y, tid = threadIdx.x;
    const float* base = P + (size_t)f * G * (KK * DD) + (size_t)k * DD + tid;

    float s = 0.0f;
    int g = 0;
    for (; g + 8 <= G; g += 8) {
        float v[8];
        #pragma unroll
        for (int u = 0; u < 8; ++u) v[u] = base[(size_t)(g + u) * (KK * DD)];
        #pragma unroll
        for (int u = 0; u < 8; ++u) s += v[u];
    }
    for (; g < G; ++g) s += base[(size_t)g * (KK * DD)];

    float c = 0.0f;
    const float* cb = C + (size_t)f * G * KK + k;
    for (int g2 = 0; g2 < G; ++g2) c += cb[(size_t)g2 * KK];

    const float m = s / c;
    float sq = m * m;
    #pragma unroll
    for (int i = 1; i < 64; i <<= 1) sq += __shfl_xor(sq, i, 64);
    __shared__ float red[4];
    const int wid = tid >> 6, lane = tid & 63;
    if (lane == 0) red[wid] = sq;
    __syncthreads();
    const float nrm = red[0] + red[1] + red[2] + red[3];
    AR[(size_t)f * KK * DD + (size_t)k * DD + tid] = m / fmaxf(sqrtf(nrm), 1e-12f);
}

__global__ __launch_bounds__(256) void loss_kernel(const float* __restrict__ AR,
                                                   float* __restrict__ lossk)
{
    const float* A = AR;
    const float* R = AR + KK * DD;
    const int k = blockIdx.x, tid = threadIdx.x;

    const float a = A[k * DD + tid];
    const float r = R[k * DD + tid];
    const float lfp = a * r * INV_TAU;
    const float fp = expf(lfp);
    float ssa = 0.0f, ssr = 0.0f;
    #pragma unroll 8
    for (int j = 0; j < KK; ++j) {
        ssa += expf(a * A[j * DD + tid] * INV_TAU);
        ssr += expf(a * R[j * DD + tid] * INV_TAU);
    }
    const float Fn = (ssa - expf(a * a * INV_TAU)) + (ssr - fp) + 2.0f * (KK - 1) * fp;
    float l = logf(Fn + EPSL) - lfp;

    #pragma unroll
    for (int i = 1; i < 64; i <<= 1) l += __shfl_xor(l, i, 64);
    __shared__ float red[4];
    const int wid = tid >> 6, lane = tid & 63;
    if (lane == 0) red[wid] = l;
    __syncthreads();
    if (tid == 0) lossk[k] = (red[0] + red[1] + red[2] + red[3]) * (1.0f / DD);
}

__global__ void final_kernel(const float* __restrict__ lossk, float* __restrict__ out)
{
    float v = lossk[threadIdx.x];
    #pragma unroll
    for (int i = 1; i < 64; i <<= 1) v += __shfl_xor(v, i, 64);
    if (threadIdx.x == 0) out[0] = v;
}

extern "C" void kernel_launch(void* const* d_in, const int* in_sizes, int n_in,
                              void* d_out, int out_size, void* d_ws, size_t ws_size,
                              hipStream_t stream)
{
    const float* fa = (const float*)d_in[0];
    const float* fr = (const float*)d_in[1];
    const int* la = (const int*)d_in[2];
    const int* lr = (const int*)d_in[3];
    float* ws = (float*)d_ws;
    float* out = (float*)d_out;
    const int N = in_sizes[2];

    float* P = ws;                                  // [2][GX][K*D]
    float* C = P + 2L * GX * KK * DD;               // [2][GX][K]
    float* AR = C + 2L * GX * KK;                   // [2][K*D]
    float* lossk = AR + 2L * KK * DD;               // [K]
    float* scratch = lossk + KK;                    // [8] probe slots

    hipMemsetAsync(scratch, 0, 8 * sizeof(float), stream);

    seg_mfma_kernel<<<dim3(GX, 2), 512, 0, stream>>>(fa, fr, la, lr, P, C, N);
    proto_norm_kernel<<<dim3(KK, 2), 256, 0, stream>>>(P, C, AR, GX);
    loss_kernel<<<KK, 256, 0, stream>>>(AR, lossk);
    final_kernel<<<1, 64, 0, stream>>>(lossk, out);

    // discriminator probes (after output; write only to scratch)
    probe_stream1_x2<<<dim3(GX, 2), 512, 0, stream>>>(fa, fr, scratch, N);
    probe_stream4_x2<<<dim3(GX, 2), 512, 0, stream>>>(fa, fr, scratch, N);
}

// Round 12
// 150.570 us; speedup vs baseline: 1.8855x; 1.8211x over previous
//
#include <hip/hip_runtime.h>
#include <math.h>

#define KK 64
#define DD 256
#define GX 256        // blocks per feature; grid = 512 = 2 blocks/CU
#define CH 16         // rows per MFMA chunk (K of 32x32x16)
#define MAXCHUNK 512  // max rows per block (N <= GX*MAXCHUNK)
#define INV_TAU 2.0f
#define EPSL 1e-8f

typedef unsigned int u32;
typedef __attribute__((ext_vector_type(4))) u32 u32x4;
typedef __attribute__((ext_vector_type(8))) short s16x8;
typedef __attribute__((ext_vector_type(16))) float f32x16;

__device__ __forceinline__ u32 f2bf(float f) {
    u32 u = __builtin_bit_cast(u32, f);
    return (u + 0x7FFFu + ((u >> 16) & 1u)) >> 16;
}

// ws float layout:
// P : [2][GX][K*D]; C : [2][GX][K]; AR : [2][K*D]; lossk : [K]; scratch : [8]

__global__ __launch_bounds__(512, 4) void seg_mfma_kernel(
    const float* __restrict__ fa, const float* __restrict__ fr,
    const int* __restrict__ la, const int* __restrict__ lr,
    float* __restrict__ P, float* __restrict__ C, int N)
{
    __shared__ int lbl[MAXCHUNK];
    __shared__ int cnt[KK];

    const int tid = threadIdx.x;
    const int g = blockIdx.x, f = blockIdx.y;
    const float* __restrict__ feat = f ? fr : fa;
    const int* __restrict__ label = f ? lr : la;

    if (tid < KK) cnt[tid] = 0;

    const int chunkR = (N + GX - 1) / GX;
    const int n0 = g * chunkR;
    int rows = min(N, n0 + chunkR) - n0;
    if (rows < 0) rows = 0;

    __syncthreads();
    for (int i = tid; i < rows; i += 512) lbl[i] = label[n0 + i];
    __syncthreads();
    for (int i = tid; i < rows; i += 512) atomicAdd(&cnt[lbl[i]], 1);

    const int w = tid >> 6, lane = tid & 63;
    const int half = lane >> 5;       // K half-group (rows half*8 .. half*8+7)
    const int nn = lane & 31;         // class-in-group / col-in-strip
    const int col0 = w * 32;          // wave owns cols [32w, 32w+32)

    f32x16 acc0 = {0.0f}, acc1 = {0.0f};
    const int nfull = rows / CH;

    #define LOADF(dst, t)                                                        \
    do {                                                                         \
        const float* bp_ = feat + (size_t)(n0 + (t) * CH + half * 8) * DD + col0 + nn; \
        _Pragma("unroll")                                                        \
        for (int j_ = 0; j_ < 8; ++j_) dst[j_] = bp_[j_ * DD];                   \
    } while (0)

    #define PACK_MFMA(vc, lv)                                                    \
    do {                                                                         \
        u32 a0p[4], a1p[4], bpk[4];                                              \
        _Pragma("unroll")                                                        \
        for (int p_ = 0; p_ < 4; ++p_) {                                         \
            const int j0_ = 2 * p_, j1_ = 2 * p_ + 1;                            \
            a0p[p_] = ((lv[j0_] == nn)      ? 0x3F80u : 0u) |                    \
                      ((lv[j1_] == nn)      ? 0x3F800000u : 0u);                 \
            a1p[p_] = ((lv[j0_] == nn + 32) ? 0x3F80u : 0u) |                    \
                      ((lv[j1_] == nn + 32) ? 0x3F800000u : 0u);                 \
            bpk[p_] = f2bf(vc[j0_]) | (f2bf(vc[j1_]) << 16);                     \
        }                                                                        \
        const s16x8 A0 = __builtin_bit_cast(s16x8, (u32x4){a0p[0], a0p[1], a0p[2], a0p[3]}); \
        const s16x8 A1 = __builtin_bit_cast(s16x8, (u32x4){a1p[0], a1p[1], a1p[2], a1p[3]}); \
        const s16x8 Bf = __builtin_bit_cast(s16x8, (u32x4){bpk[0], bpk[1], bpk[2], bpk[3]}); \
        acc0 = __builtin_amdgcn_mfma_f32_32x32x16_bf16(A0, Bf, acc0, 0, 0, 0);   \
        acc1 = __builtin_amdgcn_mfma_f32_32x32x16_bf16(A1, Bf, acc1, 0, 0, 0);   \
    } while (0)

    #define DO_CHUNK(vc, t)                                                      \
    do {                                                                         \
        int lv[8];                                                               \
        const int rb_ = (t) * CH + half * 8;                                     \
        _Pragma("unroll")                                                        \
        for (int j_ = 0; j_ < 8; ++j_) lv[j_] = lbl[rb_ + j_];                   \
        PACK_MFMA(vc, lv);                                                       \
    } while (0)

    // depth-4 pipeline: 4 named buffers (rule #20), 32 dword loads = 8 KB/wave
    // in flight; compiler emits counted vmcnt (24 younger) before each consume.
    float b0[8], b1[8], b2[8], b3[8];
    if (nfull > 0) LOADF(b0, 0);
    if (nfull > 1) LOADF(b1, 1);
    if (nfull > 2) LOADF(b2, 2);
    if (nfull > 3) LOADF(b3, 3);
    for (int t = 0; t < nfull; t += 4) {
        { DO_CHUNK(b0, t); if (t + 4 < nfull) LOADF(b0, t + 4); }
        if (t + 1 < nfull) { DO_CHUNK(b1, t + 1); if (t + 5 < nfull) LOADF(b1, t + 5); }
        if (t + 2 < nfull) { DO_CHUNK(b2, t + 2); if (t + 6 < nfull) LOADF(b2, t + 6); }
        if (t + 3 < nfull) { DO_CHUNK(b3, t + 3); if (t + 7 < nfull) LOADF(b3, t + 7); }
    }

    // row tail (rows % 16), clamped
    if (nfull * CH < rows) {
        const int r0 = nfull * CH + half * 8;
        float tv[8];
        int lv[8];
        #pragma unroll
        for (int j = 0; j < 8; ++j) {
            const int rr = r0 + j;
            lv[j] = (rr < rows) ? lbl[rr] : -1;
            tv[j] = feat[(size_t)(n0 + ((rr < rows) ? rr : 0)) * DD + col0 + nn];
        }
        PACK_MFMA(tv, lv);
    }
    #undef LOADF
    #undef PACK_MFMA
    #undef DO_CHUNK

    // epilogue: D layout (HW-verified): col = lane&31, class = (rg&3)+8*(rg>>2)+4*half
    float* dstb = P + ((size_t)f * GX + g) * (KK * DD);
    #pragma unroll
    for (int rg = 0; rg < 16; ++rg) {
        const int cls = (rg & 3) + 8 * (rg >> 2) + 4 * half;
        dstb[(size_t)cls * DD + col0 + nn] = acc0[rg];
        dstb[(size_t)(cls + 32) * DD + col0 + nn] = acc1[rg];
    }
    __syncthreads();
    if (tid < KK) C[((size_t)f * GX + g) * KK + tid] = (float)cnt[tid];
}

// ---------- discriminator probe (ws scratch only; output unaffected) ----------

__device__ __forceinline__ void probe_flush(float s, float* slot) {
    #pragma unroll
    for (int d = 1; d < 64; d <<= 1) s += __shfl_xor(s, d, 64);
    __shared__ float red[8];
    const int tid = threadIdx.x;
    if ((tid & 63) == 0) red[tid >> 6] = s;
    __syncthreads();
    if (tid == 0) {
        float t = 0;
        #pragma unroll
        for (int u = 0; u < 8; ++u) t += red[u];
        atomicAdd(slot, t);
    }
}

// identical depth-4 dword load structure, adds instead of pack+MFMA
__global__ __launch_bounds__(512, 4) void probe_d4a(
    const float* __restrict__ fa, const float* __restrict__ fr,
    float* __restrict__ scratch, int N)
{
    const int tid = threadIdx.x, g = blockIdx.x, f = blockIdx.y;
    const float* feat = f ? fr : fa;
    const int chunkR = (N + GX - 1) / GX;
    const int n0 = g * chunkR;
    int rows = min(N, n0 + chunkR) - n0;
    if (rows < 0) rows = 0;
    const int w = tid >> 6, lane = tid & 63;
    const int half = lane >> 5;
    const int col0 = w * 32, nn = lane & 31;
    const int nfull = rows / CH;

    #define LOADF(dst, t)                                                        \
    do {                                                                         \
        const float* bp_ = feat + (size_t)(n0 + (t) * CH + half * 8) * DD + col0 + nn; \
        _Pragma("unroll")                                                        \
        for (int j_ = 0; j_ < 8; ++j_) dst[j_] = bp_[j_ * DD];                   \
    } while (0)
    #define CONS(vc)                                                             \
    do { _Pragma("unroll") for (int j_ = 0; j_ < 8; ++j_) s += vc[j_]; } while (0)

    float s = 0.0f;
    float b0[8], b1[8], b2[8], b3[8];
    if (nfull > 0) LOADF(b0, 0);
    if (nfull > 1) LOADF(b1, 1);
    if (nfull > 2) LOADF(b2, 2);
    if (nfull > 3) LOADF(b3, 3);
    for (int t = 0; t < nfull; t += 4) {
        { CONS(b0); if (t + 4 < nfull) LOADF(b0, t + 4); }
        if (t + 1 < nfull) { CONS(b1); if (t + 5 < nfull) LOADF(b1, t + 5); }
        if (t + 2 < nfull) { CONS(b2); if (t + 6 < nfull) LOADF(b2, t + 6); }
        if (t + 3 < nfull) { CONS(b3); if (t + 7 < nfull) LOADF(b3, t + 7); }
    }
    #undef LOADF
    #undef CONS
    probe_flush(s, &scratch[f]);
}

// ---------- downstream (unchanged, proven) ----------

__global__ __launch_bounds__(256) void proto_norm_kernel(
    const float* __restrict__ P, const float* __restrict__ C,
    float* __restrict__ AR, int G)
{
    const int k = blockIdx.x, f = blockIdx.y, tid = threadIdx.x;
    const float* base = P + (size_t)f * G * (KK * DD) + (size_t)k * DD + tid;

    float s = 0.0f;
    int g = 0;
    for (; g + 8 <= G; g += 8) {
        float v[8];
        #pragma unroll
        for (int u = 0; u < 8; ++u) v[u] = base[(size_t)(g + u) * (KK * DD)];
        #pragma unroll
        for (int u = 0; u < 8; ++u) s += v[u];
    }
    for (; g < G; ++g) s += base[(size_t)g * (KK * DD)];

    float c = 0.0f;
    const float* cb = C + (size_t)f * G * KK + k;
    for (int g2 = 0; g2 < G; ++g2) c += cb[(size_t)g2 * KK];

    const float m = s / c;
    float sq = m * m;
    #pragma unroll
    for (int i = 1; i < 64; i <<= 1) sq += __shfl_xor(sq, i, 64);
    __shared__ float red[4];
    const int wid = tid >> 6, lane = tid & 63;
    if (lane == 0) red[wid] = sq;
    __syncthreads();
    const float nrm = red[0] + red[1] + red[2] + red[3];
    AR[(size_t)f * KK * DD + (size_t)k * DD + tid] = m / fmaxf(sqrtf(nrm), 1e-12f);
}

__global__ __launch_bounds__(256) void loss_kernel(const float* __restrict__ AR,
                                                   float* __restrict__ lossk)
{
    const float* A = AR;
    const float* R = AR + KK * DD;
    const int k = blockIdx.x, tid = threadIdx.x;

    const float a = A[k * DD + tid];
    const float r = R[k * DD + tid];
    const float lfp = a * r * INV_TAU;
    const float fp = expf(lfp);
    float ssa = 0.0f, ssr = 0.0f;
    #pragma unroll 8
    for (int j = 0; j < KK; ++j) {
        ssa += expf(a * A[j * DD + tid] * INV_TAU);
        ssr += expf(a * R[j * DD + tid] * INV_TAU);
    }
    const float Fn = (ssa - expf(a * a * INV_TAU)) + (ssr - fp) + 2.0f * (KK - 1) * fp;
    float l = logf(Fn + EPSL) - lfp;

    #pragma unroll
    for (int i = 1; i < 64; i <<= 1) l += __shfl_xor(l, i, 64);
    __shared__ float red[4];
    const int wid = tid >> 6, lane = tid & 63;
    if (lane == 0) red[wid] = l;
    __syncthreads();
    if (tid == 0) lossk[k] = (red[0] + red[1] + red[2] + red[3]) * (1.0f / DD);
}

__global__ void final_kernel(const float* __restrict__ lossk, float* __restrict__ out)
{
    float v = lossk[threadIdx.x];
    #pragma unroll
    for (int i = 1; i < 64; i <<= 1) v += __shfl_xor(v, i, 64);
    if (threadIdx.x == 0) out[0] = v;
}

extern "C" void kernel_launch(void* const* d_in, const int* in_sizes, int n_in,
                              void* d_out, int out_size, void* d_ws, size_t ws_size,
                              hipStream_t stream)
{
    const float* fa = (const float*)d_in[0];
    const float* fr = (const float*)d_in[1];
    const int* la = (const int*)d_in[2];
    const int* lr = (const int*)d_in[3];
    float* ws = (float*)d_ws;
    float* out = (float*)d_out;
    const int N = in_sizes[2];

    float* P = ws;                                  // [2][GX][K*D]
    float* C = P + 2L * GX * KK * DD;               // [2][GX][K]
    float* AR = C + 2L * GX * KK;                   // [2][K*D]
    float* lossk = AR + 2L * KK * DD;               // [K]
    float* scratch = lossk + KK;                    // [8] probe slots (never read)

    seg_mfma_kernel<<<dim3(GX, 2), 512, 0, stream>>>(fa, fr, la, lr, P, C, N);
    proto_norm_kernel<<<dim3(KK, 2), 256, 0, stream>>>(P, C, AR, GX);
    loss_kernel<<<KK, 256, 0, stream>>>(AR, lossk);
    final_kernel<<<1, 64, 0, stream>>>(lossk, out);

    // discriminator: same depth-4 loads, no pack/MFMA
    probe_d4a<<<dim3(GX, 2), 512, 0, stream>>>(fa, fr, scratch, N);
}

// Round 13
// 117.511 us; speedup vs baseline: 2.4159x; 1.2813x over previous
//
#include <hip/hip_runtime.h>
#include <math.h>

#define KK 64
#define DD 256
#define GX 256        // blocks per feature; grid = 512 = 2 blocks/CU
#define CH 16         // rows per MFMA chunk (K of 32x32x16)
#define MAXCHUNK 512  // max rows per block (N <= GX*MAXCHUNK)
#define INV_TAU 2.0f
#define EPSL 1e-8f

typedef unsigned int u32;
typedef __attribute__((ext_vector_type(4))) u32 u32x4;
typedef __attribute__((ext_vector_type(8))) short s16x8;
typedef __attribute__((ext_vector_type(16))) float f32x16;

__device__ __forceinline__ u32 f2bf(float f) {
    u32 u = __builtin_bit_cast(u32, f);
    return (u + 0x7FFFu + ((u >> 16) & 1u)) >> 16;
}

// ws float layout:
// P : [2][GX][K*D]; C : [2][GX][K]; AR : [2][K*D]; lossk : [K]

__global__ __launch_bounds__(512, 4) void seg_mfma_kernel(
    const float* __restrict__ fa, const float* __restrict__ fr,
    const int* __restrict__ la, const int* __restrict__ lr,
    float* __restrict__ P, float* __restrict__ C, int N)
{
    __shared__ int lbl[MAXCHUNK];
    __shared__ int cnt[KK];

    const int tid = threadIdx.x;
    const int g = blockIdx.x, f = blockIdx.y;
    const float* __restrict__ feat = f ? fr : fa;
    const int* __restrict__ label = f ? lr : la;

    if (tid < KK) cnt[tid] = 0;

    const int chunkR = (N + GX - 1) / GX;
    const int n0 = g * chunkR;
    int rows = min(N, n0 + chunkR) - n0;
    if (rows < 0) rows = 0;

    __syncthreads();
    for (int i = tid; i < rows; i += 512) lbl[i] = label[n0 + i];
    __syncthreads();
    for (int i = tid; i < rows; i += 512) atomicAdd(&cnt[lbl[i]], 1);

    const int w = tid >> 6, lane = tid & 63;
    const int half = lane >> 5;       // K half-group (rows half*8 .. half*8+7)
    const int nn = lane & 31;         // class-in-group / col-in-strip
    const int col0 = w * 32;          // wave owns cols [32w, 32w+32)

    f32x16 acc0 = {0.0f}, acc1 = {0.0f};
    const int nfull = rows / CH;

    // per-lane byte offset within a chunk: row sub-offset (half*8 rows) + column
    const u32 voff = (u32)(half * 8 * DD + col0 + nn) * 4u;

    // pinned async loads: volatile asm keeps issue order and forces all 8
    // dest VGPRs live until consumed -> real depth-4, compiler can't sink.
    #define LOADA(dst, t)                                                       \
    do {                                                                        \
        const float* p0_ = feat + (size_t)(n0 + (t) * CH) * DD;                 \
        const float* p1_ = p0_ + 4 * DD;                                        \
        asm volatile(                                                           \
            "global_load_dword %0, %8, %9\n\t"                                  \
            "global_load_dword %1, %8, %9 offset:1024\n\t"                      \
            "global_load_dword %2, %8, %9 offset:2048\n\t"                      \
            "global_load_dword %3, %8, %9 offset:3072\n\t"                      \
            "global_load_dword %4, %8, %10\n\t"                                 \
            "global_load_dword %5, %8, %10 offset:1024\n\t"                     \
            "global_load_dword %6, %8, %10 offset:2048\n\t"                     \
            "global_load_dword %7, %8, %10 offset:3072"                         \
            : "=&v"(dst[0]), "=&v"(dst[1]), "=&v"(dst[2]), "=&v"(dst[3]),       \
              "=&v"(dst[4]), "=&v"(dst[5]), "=&v"(dst[6]), "=&v"(dst[7])        \
            : "v"(voff), "s"(p0_), "s"(p1_)                                     \
            : "memory");                                                        \
    } while (0)

    // one chunk: label reads + A-pack BEFORE the vmcnt wait (label-only work);
    // counted wait (epilogue-aware) + sched_barrier; then B-pack + 2 MFMA.
    #define STEP(buf, tt)                                                       \
    if ((tt) < nfull) {                                                         \
        const int rb_ = (tt) * CH + half * 8;                                   \
        int lv[8]; u32 a0p[4], a1p[4];                                          \
        _Pragma("unroll")                                                       \
        for (int j_ = 0; j_ < 8; ++j_) lv[j_] = lbl[rb_ + j_];                  \
        _Pragma("unroll")                                                       \
        for (int p_ = 0; p_ < 4; ++p_) {                                        \
            const int j0_ = 2 * p_, j1_ = 2 * p_ + 1;                           \
            a0p[p_] = ((lv[j0_] == nn)      ? 0x3F80u : 0u) |                   \
                      ((lv[j1_] == nn)      ? 0x3F800000u : 0u);                \
            a1p[p_] = ((lv[j0_] == nn + 32) ? 0x3F80u : 0u) |                   \
                      ((lv[j1_] == nn + 32) ? 0x3F800000u : 0u);                \
        }                                                                       \
        const int rem_ = nfull - 1 - (tt);                                      \
        if (rem_ >= 3)      { asm volatile("s_waitcnt vmcnt(24)" ::: "memory"); } \
        else if (rem_ == 2) { asm volatile("s_waitcnt vmcnt(16)" ::: "memory"); } \
        else if (rem_ == 1) { asm volatile("s_waitcnt vmcnt(8)"  ::: "memory"); } \
        else                { asm volatile("s_waitcnt vmcnt(0)"  ::: "memory"); } \
        __builtin_amdgcn_sched_barrier(0);                                      \
        u32 bpk[4];                                                             \
        _Pragma("unroll")                                                       \
        for (int p_ = 0; p_ < 4; ++p_)                                          \
            bpk[p_] = f2bf(buf[2 * p_]) | (f2bf(buf[2 * p_ + 1]) << 16);        \
        const s16x8 A0 = __builtin_bit_cast(s16x8, (u32x4){a0p[0], a0p[1], a0p[2], a0p[3]}); \
        const s16x8 A1 = __builtin_bit_cast(s16x8, (u32x4){a1p[0], a1p[1], a1p[2], a1p[3]}); \
        const s16x8 Bf = __builtin_bit_cast(s16x8, (u32x4){bpk[0], bpk[1], bpk[2], bpk[3]}); \
        acc0 = __builtin_amdgcn_mfma_f32_32x32x16_bf16(A0, Bf, acc0, 0, 0, 0);  \
        acc1 = __builtin_amdgcn_mfma_f32_32x32x16_bf16(A1, Bf, acc1, 0, 0, 0);  \
        if ((tt) + 4 < nfull) LOADA(buf, (tt) + 4);                             \
    }

    float b0[8], b1[8], b2[8], b3[8];
    if (nfull > 0) LOADA(b0, 0);
    if (nfull > 1) LOADA(b1, 1);
    if (nfull > 2) LOADA(b2, 2);
    if (nfull > 3) LOADA(b3, 3);
    for (int t = 0; t < nfull; t += 4) {
        STEP(b0, t)
        STEP(b1, t + 1)
        STEP(b2, t + 2)
        STEP(b3, t + 3)
    }

    // row tail (rows % 16), clamped, compiler-tracked loads (vmcnt already 0)
    if (nfull * CH < rows) {
        const int r0 = nfull * CH + half * 8;
        float tv[8];
        int lv[8];
        #pragma unroll
        for (int j = 0; j < 8; ++j) {
            const int rr = r0 + j;
            lv[j] = (rr < rows) ? lbl[rr] : -1;
            tv[j] = feat[(size_t)(n0 + ((rr < rows) ? rr : 0)) * DD + col0 + nn];
        }
        u32 a0p[4], a1p[4], bpk[4];
        #pragma unroll
        for (int p = 0; p < 4; ++p) {
            const int j0 = 2 * p, j1 = 2 * p + 1;
            a0p[p] = ((lv[j0] == nn)      ? 0x3F80u : 0u) |
                     ((lv[j1] == nn)      ? 0x3F800000u : 0u);
            a1p[p] = ((lv[j0] == nn + 32) ? 0x3F80u : 0u) |
                     ((lv[j1] == nn + 32) ? 0x3F800000u : 0u);
            bpk[p] = f2bf(tv[j0]) | (f2bf(tv[j1]) << 16);
        }
        const s16x8 A0 = __builtin_bit_cast(s16x8, (u32x4){a0p[0], a0p[1], a0p[2], a0p[3]});
        const s16x8 A1 = __builtin_bit_cast(s16x8, (u32x4){a1p[0], a1p[1], a1p[2], a1p[3]});
        const s16x8 Bf = __builtin_bit_cast(s16x8, (u32x4){bpk[0], bpk[1], bpk[2], bpk[3]});
        acc0 = __builtin_amdgcn_mfma_f32_32x32x16_bf16(A0, Bf, acc0, 0, 0, 0);
        acc1 = __builtin_amdgcn_mfma_f32_32x32x16_bf16(A1, Bf, acc1, 0, 0, 0);
    }
    #undef LOADA
    #undef STEP

    // epilogue: D layout (HW-verified): col = lane&31, class = (rg&3)+8*(rg>>2)+4*half
    float* dstb = P + ((size_t)f * GX + g) * (KK * DD);
    #pragma unroll
    for (int rg = 0; rg < 16; ++rg) {
        const int cls = (rg & 3) + 8 * (rg >> 2) + 4 * half;
        dstb[(size_t)cls * DD + col0 + nn] = acc0[rg];
        dstb[(size_t)(cls + 32) * DD + col0 + nn] = acc1[rg];
    }
    __syncthreads();
    if (tid < KK) C[((size_t)f * GX + g) * KK + tid] = (float)cnt[tid];
}

// ---------- downstream (unchanged, proven) ----------

__global__ __launch_bounds__(256) void proto_norm_kernel(
    const float* __restrict__ P, const float* __restrict__ C,
    float* __restrict__ AR, int G)
{
    const int k = blockIdx.x, f = blockIdx.y, tid = threadIdx.x;
    const float* base = P + (size_t)f * G * (KK * DD) + (size_t)k * DD + tid;

    float s = 0.0f;
    int g = 0;
    for (; g + 8 <= G; g += 8) {
        float v[8];
        #pragma unroll
        for (int u = 0; u < 8; ++u) v[u] = base[(size_t)(g + u) * (KK * DD)];
        #pragma unroll
        for (int u = 0; u < 8; ++u) s += v[u];
    }
    for (; g < G; ++g) s += base[(size_t)g * (KK * DD)];

    float c = 0.0f;
    const float* cb = C + (size_t)f * G * KK + k;
    for (int g2 = 0; g2 < G; ++g2) c += cb[(size_t)g2 * KK];

    const float m = s / c;
    float sq = m * m;
    #pragma unroll
    for (int i = 1; i < 64; i <<= 1) sq += __shfl_xor(sq, i, 64);
    __shared__ float red[4];
    const int wid = tid >> 6, lane = tid & 63;
    if (lane == 0) red[wid] = sq;
    __syncthreads();
    const float nrm = red[0] + red[1] + red[2] + red[3];
    AR[(size_t)f * KK * DD + (size_t)k * DD + tid] = m / fmaxf(sqrtf(nrm), 1e-12f);
}

__global__ __launch_bounds__(256) void loss_kernel(const float* __restrict__ AR,
                                                   float* __restrict__ lossk)
{
    const float* A = AR;
    const float* R = AR + KK * DD;
    const int k = blockIdx.x, tid = threadIdx.x;

    const float a = A[k * DD + tid];
    const float r = R[k * DD + tid];
    const float lfp = a * r * INV_TAU;
    const float fp = expf(lfp);
    float ssa = 0.0f, ssr = 0.0f;
    #pragma unroll 8
    for (int j = 0; j < KK; ++j) {
        ssa += expf(a * A[j * DD + tid] * INV_TAU);
        ssr += expf(a * R[j * DD + tid] * INV_TAU);
    }
    const float Fn = (ssa - expf(a * a * INV_TAU)) + (ssr - fp) + 2.0f * (KK - 1) * fp;
    float l = logf(Fn + EPSL) - lfp;

    #pragma unroll
    for (int i = 1; i < 64; i <<= 1) l += __shfl_xor(l, i, 64);
    __shared__ float red[4];
    const int wid = tid >> 6, lane = tid & 63;
    if (lane == 0) red[wid] = l;
    __syncthreads();
    if (tid == 0) lossk[k] = (red[0] + red[1] + red[2] + red[3]) * (1.0f / DD);
}

__global__ void final_kernel(const float* __restrict__ lossk, float* __restrict__ out)
{
    float v = lossk[threadIdx.x];
    #pragma unroll
    for (int i = 1; i < 64; i <<= 1) v += __shfl_xor(v, i, 64);
    if (threadIdx.x == 0) out[0] = v;
}

extern "C" void kernel_launch(void* const* d_in, const int* in_sizes, int n_in,
                              void* d_out, int out_size, void* d_ws, size_t ws_size,
                              hipStream_t stream)
{
    const float* fa = (const float*)d_in[0];
    const float* fr = (const float*)d_in[1];
    const int* la = (const int*)d_in[2];
    const int* lr = (const int*)d_in[3];
    float* ws = (float*)d_ws;
    float* out = (float*)d_out;
    const int N = in_sizes[2];

    float* P = ws;                                  // [2][GX][K*D]
    float* C = P + 2L * GX * KK * DD;               // [2][GX][K]
    float* AR = C + 2L * GX * KK;                   // [2][K*D]
    float* lossk = AR + 2L * KK * DD;               // [K]

    seg_mfma_kernel<<<dim3(GX, 2), 512, 0, stream>>>(fa, fr, la, lr, P, C, N);
    proto_norm_kernel<<<dim3(KK, 2), 256, 0, stream>>>(P, C, AR, GX);
    loss_kernel<<<KK, 256, 0, stream>>>(AR, lossk);
    final_kernel<<<1, 64, 0, stream>>>(lossk, out);
}